// Round 6
// baseline (603.965 us; speedup 1.0000x reference)
//
#include <hip/hip_runtime.h>
#include <hip/hip_bf16.h>
#include <stdint.h>

#define B_ 2
#define Qn 2048
#define Kn 2048
#define Hn 16
#define Dn 128
#define QT 32      // q rows per block (2 waves x 16)
#define KT 32      // keys per K-tile
#define HD (Hn*Dn)
#define KROW 136   // Ksm row stride in shorts (272 B)
#define VROW 40    // Vt  row stride in shorts (80 B)

typedef __bf16 bf16x8 __attribute__((ext_vector_type(8)));
typedef float f32x4 __attribute__((ext_vector_type(4)));
typedef unsigned short u16x4_t __attribute__((ext_vector_type(4)));

union BF8 { unsigned short u[8]; bf16x8 v; };
union BF4 { unsigned short u[4]; u16x4_t v; };

__device__ __forceinline__ unsigned short f2bf(float f) {
  union { float f; uint32_t u; } x; x.f = f;
  uint32_t r = x.u + 0x7FFFu + ((x.u >> 16) & 1u);   // round-to-nearest-even
  return (unsigned short)(r >> 16);
}

__global__ __launch_bounds__(128, 4) void attn_fwd(
    const float* __restrict__ qs, const float* __restrict__ ks,
    const float* __restrict__ vs, const int* __restrict__ vlen,
    float* __restrict__ ctx_out, float* __restrict__ attn_out)
{
  // single-buffered bf16 tiles (small LDS -> 8 blocks/CU; cross-block overlap
  // replaces intra-block double-buffering)
  __shared__ __align__(16) unsigned short Ksm[KT][KROW];  // row-major K
  __shared__ __align__(16) unsigned short Vt [Dn][VROW];  // V^T, pair-ordered chunks

  const int tid  = threadIdx.x;
  const int wave = tid >> 6;
  const int lane = tid & 63;
  const int c = lane & 15;      // fragment index: q-row (B of QK^T) / dout (A of PV)
  const int g = lane >> 4;      // k-group

  // XCD-aware decode: xcd = L&7 pins a bh-group to one XCD (K/V panels L2-local)
  const int L   = blockIdx.x;
  const int xcd = L & 7;
  const int i5  = L >> 3;                 // 0..255
  const int bh  = ((i5 & 3) << 3) + xcd;  // 4 bh per XCD, batches mixed
  const int qt  = i5 >> 2;                // 0..63
  const int b   = bh >> 4;                // Hn = 16
  const int h   = bh & 15;
  const int vl  = vlen[b];
  const int qb  = qt * QT + wave * 16;

  // ---- hoisted Q fragments: element j of group g holds d = s*32 + g*8 + j ----
  BF8 qf[4];
  {
    const float* qrow = qs + (((size_t)(b * Qn + qb + c)) * Hn + h) * Dn;
    #pragma unroll
    for (int s = 0; s < 4; ++s) {
      f32x4 a0 = *(const f32x4*)(qrow + s * 32 + g * 8);
      f32x4 a1 = *(const f32x4*)(qrow + s * 32 + g * 8 + 4);
      #pragma unroll
      for (int j = 0; j < 4; ++j) { qf[s].u[j] = f2bf(a0[j]); qf[s].u[4 + j] = f2bf(a1[j]); }
    }
  }

  const float scale = 0.088388347648318447f;  // 1/sqrt(128)
  const int nkt_v = (vl + KT - 1) / KT;
  const float* kbase = ks + ((size_t)b * Kn * Hn + h) * Dn;
  const float* vbase = vs + ((size_t)b * Kn * Hn + h) * Dn;

  // K tile: 32 rows x 32 f32x4-chunks = 1024 chunks, 128 threads -> 8 each
  #define STAGE_K(kt) do { \
    const float* kb_p = kbase + (size_t)(kt) * KT * HD; \
    _Pragma("unroll") \
    for (int ii = 0; ii < 8; ++ii) { \
      int chunk = ii * 128 + tid; \
      int row = chunk >> 5, cv = chunk & 31; \
      f32x4 a = *(const f32x4*)(kb_p + (size_t)row * HD + cv * 4); \
      BF4 t; \
      _Pragma("unroll") \
      for (int j = 0; j < 4; ++j) t.u[j] = f2bf(a[j]); \
      *(u16x4_t*)&Ksm[row][cv * 4] = t.v; \
    } } while (0)

  // V^T staging: chunk gg of row d holds keys {4gg..4gg+3, 16+4gg..16+4gg+3}
  // 128 d-rows x 4 chunks, 128 threads -> 4 chunks each (row d = tid)
  #define STAGE_V(kt) do { \
    const float* colp = vbase + (size_t)(kt) * KT * HD + tid; \
    _Pragma("unroll") \
    for (int gg = 0; gg < 4; ++gg) { \
      BF8 t; \
      _Pragma("unroll") \
      for (int j = 0; j < 4; ++j) t.u[j]     = f2bf(colp[(size_t)(4 * gg + j) * HD]); \
      _Pragma("unroll") \
      for (int j = 0; j < 4; ++j) t.u[4 + j] = f2bf(colp[(size_t)(16 + 4 * gg + j) * HD]); \
      *(bf16x8*)&Vt[tid][gg * 8] = t.v; \
    } } while (0)

  // ---------------- pass 1: row sums of exp (swapped QK^T -> S^T) ----------------
  float rs = 0.f;
  for (int kt = 0; kt < nkt_v; ++kt) {
    STAGE_K(kt);
    __syncthreads();
    #pragma unroll
    for (int nt = 0; nt < 2; ++nt) {
      f32x4 acc = {0.f, 0.f, 0.f, 0.f};
      #pragma unroll
      for (int s = 0; s < 4; ++s) {
        BF8 kf; kf.v = *(const bf16x8*)&Ksm[nt * 16 + c][s * 32 + g * 8];
        acc = __builtin_amdgcn_mfma_f32_16x16x32_bf16(kf.v, qf[s].v, acc, 0, 0, 0);
      }
      const int k0 = kt * KT + nt * 16 + g * 4;
      #pragma unroll
      for (int r = 0; r < 4; ++r)
        rs += (k0 + r < vl) ? __expf(acc[r] * scale) : 0.f;
    }
    __syncthreads();
  }
  rs += __shfl_xor(rs, 16);
  rs += __shfl_xor(rs, 32);
  const float inv = 1.0f / rs;   // row sum for q-row (qb + c)

  // ---------------- pass 2: attn (vector stores) + PV from register P ----------------
  f32x4 ctxa[8];
  #pragma unroll
  for (int ii = 0; ii < 8; ++ii) ctxa[ii] = (f32x4){0.f, 0.f, 0.f, 0.f};

  float* rowp = attn_out + ((size_t)bh * Qn + qb + c) * Kn;
  for (int kt = 0; kt < nkt_v; ++kt) {
    STAGE_K(kt);
    STAGE_V(kt);
    __syncthreads();

    // S^T: lane (c,g) holds S[q=c][k = kt*32 + nt*16 + g*4 + r]
    BF8 pf;
    #pragma unroll
    for (int nt = 0; nt < 2; ++nt) {
      f32x4 acc = {0.f, 0.f, 0.f, 0.f};
      #pragma unroll
      for (int s = 0; s < 4; ++s) {
        BF8 kf; kf.v = *(const bf16x8*)&Ksm[nt * 16 + c][s * 32 + g * 8];
        acc = __builtin_amdgcn_mfma_f32_16x16x32_bf16(kf.v, qf[s].v, acc, 0, 0, 0);
      }
      const int k0 = kt * KT + nt * 16 + g * 4;
      f32x4 p;
      #pragma unroll
      for (int r = 0; r < 4; ++r) {
        p[r] = (k0 + r < vl) ? __expf(acc[r] * scale) * inv : 0.f;
        pf.u[nt * 4 + r] = f2bf(p[r]);
      }
      *(f32x4*)(rowp + kt * KT + nt * 16 + g * 4) = p;   // 16B vector attn store
    }

    // PV (swapped): ctx^T = V^T * P^T, shared k-permutation {4g+j, 16+4g+j}
    #pragma unroll
    for (int n8 = 0; n8 < 8; ++n8) {
      BF8 vf; vf.v = *(const bf16x8*)&Vt[n8 * 16 + c][g * 8];
      ctxa[n8] = __builtin_amdgcn_mfma_f32_16x16x32_bf16(vf.v, pf.v, ctxa[n8], 0, 0, 0);
    }
    __syncthreads();
  }

  // ---------------- vectorized zero-fill of fully-masked attn columns ----------------
  const int col0 = nkt_v * KT;   // cols >= col0 are exactly 0
  #pragma unroll 1
  for (int r = 0; r < 16; ++r) {
    float* zp = attn_out + ((size_t)bh * Qn + qb + r) * Kn;   // wave's own 16 rows
    for (int c4 = col0 + lane * 4; c4 < Kn; c4 += 256)
      *(f32x4*)(zp + c4) = (f32x4){0.f, 0.f, 0.f, 0.f};
  }

  // ---------------- epilogue: ctx[q=c][d = n8*16 + g*4 + r], f32x4 stores ----------------
  float* cp = ctx_out + ((size_t)(b * Qn + qb + c) * Hn + h) * Dn;
  #pragma unroll
  for (int n8 = 0; n8 < 8; ++n8)
    *(f32x4*)(cp + n8 * 16 + g * 4) = ctxa[n8];
}

extern "C" void kernel_launch(void* const* d_in, const int* in_sizes, int n_in,
                              void* d_out, int out_size, void* d_ws, size_t ws_size,
                              hipStream_t stream) {
  const float* qs   = (const float*)d_in[0];
  const float* ks   = (const float*)d_in[1];
  const float* vs   = (const float*)d_in[2];
  const int*   vlen = (const int*)d_in[3];
  float* ctx  = (float*)d_out;
  float* attn = ctx + (size_t)B_ * Qn * Hn * Dn;   // outputs concatenated: ctx, attn
  attn_fwd<<<dim3((Qn / QT) * B_ * Hn), 128, 0, stream>>>(qs, ks, vs, vlen, ctx, attn);
}

// Round 7
// 277.627 us; speedup vs baseline: 2.1755x; 2.1755x over previous
//
#include <hip/hip_runtime.h>
#include <hip/hip_bf16.h>
#include <stdint.h>

#define B_ 2
#define Qn 2048
#define Kn 2048
#define Hn 16
#define Dn 128
#define QT 128     // q rows per block (8 waves x 16)
#define KT 32      // keys per K-tile
#define HD (Hn*Dn)
#define KROW 132   // Ksm row stride in shorts (264 B)
#define VROW 36    // Vt  row stride in shorts (72 B)
#define NQ (B_*Hn*Qn)                     // 65536 (bh,q) rows
#define CTXN ((size_t)B_*Qn*Hn*Dn)        // 8388608 ctx elements

typedef __bf16 bf16x8 __attribute__((ext_vector_type(8)));
typedef float f32x4 __attribute__((ext_vector_type(4)));
typedef unsigned short u16x4_t __attribute__((ext_vector_type(4)));

union BF8 { unsigned short u[8]; bf16x8 v; };
union BF4 { unsigned short u[4]; u16x4_t v; };

__device__ __forceinline__ unsigned short f2bf(float f) {
  union { float f; uint32_t u; } x; x.f = f;
  uint32_t r = x.u + 0x7FFFu + ((x.u >> 16) & 1u);   // round-to-nearest-even
  return (unsigned short)(r >> 16);
}

#define SCALE 0.088388347648318447f  // 1/sqrt(128)

// ---- shared staging helpers (512-thread blocks) ----
__device__ __forceinline__ void stage_k(const float* kb_p, unsigned short (*Kdst)[KROW], int tid) {
  #pragma unroll
  for (int ii = 0; ii < 2; ++ii) {
    int chunk = ii * 512 + tid;
    int row = chunk >> 5, cv = chunk & 31;
    f32x4 a = *(const f32x4*)(kb_p + (size_t)row * HD + cv * 4);
    BF4 t;
    #pragma unroll
    for (int j = 0; j < 4; ++j) t.u[j] = f2bf(a[j]);
    *(u16x4_t*)&Kdst[row][cv * 4] = t.v;
  }
}

// V^T: chunk gg of row d holds keys {4gg..4gg+3, 16+4gg..16+4gg+3}
__device__ __forceinline__ void stage_v(const float* vb_p, unsigned short (*Vdst)[VROW], int tid) {
  int d = tid & 127, gg = tid >> 7;
  const float* colp = vb_p + d;
  BF8 t;
  #pragma unroll
  for (int j = 0; j < 4; ++j) {
    t.u[j]     = f2bf(colp[(size_t)(4 * gg + j) * HD]);
    t.u[4 + j] = f2bf(colp[(size_t)(16 + 4 * gg + j) * HD]);
  }
  *(bf16x8*)&Vdst[d][gg * 8] = t.v;
}

__device__ __forceinline__ void load_q(const float* qrow, BF8* qf, int g) {
  #pragma unroll
  for (int s = 0; s < 4; ++s) {
    f32x4 a0 = *(const f32x4*)(qrow + s * 32 + g * 8);
    f32x4 a1 = *(const f32x4*)(qrow + s * 32 + g * 8 + 4);
    #pragma unroll
    for (int j = 0; j < 4; ++j) { qf[s].u[j] = f2bf(a0[j]); qf[s].u[4 + j] = f2bf(a1[j]); }
  }
}

// ================= kernel 1: partial row sums of exp(S) =================
__global__ __launch_bounds__(512, 4) void sum_k(
    const float* __restrict__ qs, const float* __restrict__ ks,
    const int* __restrict__ vlen, float* __restrict__ rs_out)
{
  __shared__ __align__(16) unsigned short Ksm[2][KT][KROW];
  const int tid = threadIdx.x, wave = tid >> 6, lane = tid & 63;
  const int c = lane & 15, g = lane >> 4;
  const int idx = blockIdx.x;
  const int kc = idx & 3, qt = (idx >> 2) & 15, bh = idx >> 6;
  const int b = bh >> 4, h = bh & 15;
  const int vl = vlen[b];
  const int qb = qt * QT + wave * 16;
  const int kbeg = kc * 512;

  float rs = 0.f;
  const int nv = min(vl - kbeg, 512);
  if (nv > 0) {
    BF8 qf[4];
    load_q(qs + (((size_t)(b * Qn + qb + c)) * Hn + h) * Dn, qf, g);
    const float* kbase = ks + ((size_t)b * Kn * Hn + h) * Dn + (size_t)kbeg * HD;
    const int nkt = (nv + 31) >> 5;
    stage_k(kbase, Ksm[0], tid);
    __syncthreads();
    for (int t = 0; t < nkt; ++t) {
      const int cur = t & 1;
      if (t + 1 < nkt) stage_k(kbase + (size_t)(t + 1) * KT * HD, Ksm[cur ^ 1], tid);
      #pragma unroll
      for (int nt = 0; nt < 2; ++nt) {
        f32x4 acc = {0.f, 0.f, 0.f, 0.f};
        #pragma unroll
        for (int s = 0; s < 4; ++s) {
          BF8 kf; kf.v = *(const bf16x8*)&Ksm[cur][nt * 16 + c][s * 32 + g * 8];
          acc = __builtin_amdgcn_mfma_f32_16x16x32_bf16(kf.v, qf[s].v, acc, 0, 0, 0);
        }
        const int k0 = kbeg + t * KT + nt * 16 + g * 4;
        #pragma unroll
        for (int r = 0; r < 4; ++r)
          rs += (k0 + r < vl) ? __expf(acc[r] * SCALE) : 0.f;
      }
      __syncthreads();
    }
    rs += __shfl_xor(rs, 16);
    rs += __shfl_xor(rs, 32);
  }
  if (lane < 16) rs_out[(size_t)kc * NQ + (size_t)bh * Qn + qb + c] = rs;
}

// ================= kernel 2: inv = 1/sum of partials =================
__global__ void inv_k(const float* __restrict__ rs, float* __restrict__ inv) {
  int i = blockIdx.x * 256 + threadIdx.x;
  float s = rs[i] + rs[NQ + i] + rs[2 * NQ + i] + rs[3 * NQ + i];
  inv[i] = 1.0f / s;
}

// ================= kernel 3: attn write + PV partials =================
__global__ __launch_bounds__(512, 4) void attn_pv(
    const float* __restrict__ qs, const float* __restrict__ ks,
    const float* __restrict__ vs, const int* __restrict__ vlen,
    const float* __restrict__ inv_ws, float* __restrict__ ctx_out,
    float* __restrict__ ctx_part, float* __restrict__ attn_out, int chunk)
{
  __shared__ __align__(16) unsigned short Ksm[2][KT][KROW];
  __shared__ __align__(16) unsigned short Vt [2][Dn][VROW];
  const int tid = threadIdx.x, wave = tid >> 6, lane = tid & 63;
  const int c = lane & 15, g = lane >> 4;
  const int kc = blockIdx.x, qt = blockIdx.y, bh = blockIdx.z;
  const int b = bh >> 4, h = bh & 15;
  const int vl = vlen[b];
  const int qb = qt * QT + wave * 16;
  const int kbeg = kc * chunk;
  float* ctx_dst = (kc == 0) ? ctx_out : ctx_part;
  const float invr = inv_ws[(size_t)bh * Qn + qb + c];

  f32x4 ctxa[8];
  #pragma unroll
  for (int ii = 0; ii < 8; ++ii) ctxa[ii] = (f32x4){0.f, 0.f, 0.f, 0.f};

  const int nv = min(vl - kbeg, chunk);
  const int nkt = (nv > 0) ? (nv + 31) >> 5 : 0;
  if (nkt > 0) {
    BF8 qf[4];
    load_q(qs + (((size_t)(b * Qn + qb + c)) * Hn + h) * Dn, qf, g);
    const float* kbase = ks + ((size_t)b * Kn * Hn + h) * Dn + (size_t)kbeg * HD;
    const float* vbase = vs + ((size_t)b * Kn * Hn + h) * Dn + (size_t)kbeg * HD;
    stage_k(kbase, Ksm[0], tid);
    stage_v(vbase, Vt[0], tid);
    __syncthreads();
    float* rowp = attn_out + ((size_t)bh * Qn + qb + c) * Kn + kbeg;
    for (int t = 0; t < nkt; ++t) {
      const int cur = t & 1;
      if (t + 1 < nkt) {
        stage_k(kbase + (size_t)(t + 1) * KT * HD, Ksm[cur ^ 1], tid);
        stage_v(vbase + (size_t)(t + 1) * KT * HD, Vt[cur ^ 1], tid);
      }
      BF8 pf;
      f32x4 pv0, pv1;
      #pragma unroll
      for (int nt = 0; nt < 2; ++nt) {
        f32x4 acc = {0.f, 0.f, 0.f, 0.f};
        #pragma unroll
        for (int s = 0; s < 4; ++s) {
          BF8 kf; kf.v = *(const bf16x8*)&Ksm[cur][nt * 16 + c][s * 32 + g * 8];
          acc = __builtin_amdgcn_mfma_f32_16x16x32_bf16(kf.v, qf[s].v, acc, 0, 0, 0);
        }
        const int k0 = kbeg + t * KT + nt * 16 + g * 4;
        #pragma unroll
        for (int r = 0; r < 4; ++r) {
          float p = (k0 + r < vl) ? __expf(acc[r] * SCALE) * invr : 0.f;
          pf.u[nt * 4 + r] = f2bf(p);
          if (nt == 0) pv0[r] = p; else pv1[r] = p;
        }
      }
      *(f32x4*)(rowp + t * KT + g * 4) = pv0;
      *(f32x4*)(rowp + t * KT + 16 + g * 4) = pv1;
      #pragma unroll
      for (int n8 = 0; n8 < 8; ++n8) {
        BF8 vf; vf.v = *(const bf16x8*)&Vt[cur][n8 * 16 + c][g * 8];
        ctxa[n8] = __builtin_amdgcn_mfma_f32_16x16x32_bf16(vf.v, pf.v, ctxa[n8], 0, 0, 0);
      }
      __syncthreads();
    }
  }

  // zero-fill masked columns inside this chunk
  const int zs = kbeg + nkt * KT;
  const int ze = kbeg + chunk;
  #pragma unroll 1
  for (int r = 0; r < 16; ++r) {
    float* zp = attn_out + ((size_t)bh * Qn + qb + r) * Kn;
    for (int c4 = zs + lane * 4; c4 < ze; c4 += 256)
      *(f32x4*)(zp + c4) = (f32x4){0.f, 0.f, 0.f, 0.f};
  }

  // ctx (or partial) store: ctx[q=c][d = n8*16 + g*4 + r]
  float* cp = ctx_dst + (((size_t)(b * Qn + qb + c)) * Hn + h) * Dn;
  #pragma unroll
  for (int n8 = 0; n8 < 8; ++n8)
    *(f32x4*)(cp + n8 * 16 + g * 4) = ctxa[n8];
}

// ================= kernel 4: fold ctx partials =================
__global__ void fold_k(float* __restrict__ ctx, const float* __restrict__ part) {
  size_t i = ((size_t)blockIdx.x * 256 + threadIdx.x) * 4;
  const size_t stride = (size_t)gridDim.x * 256 * 4;
  for (; i < CTXN; i += stride) {
    f32x4 a = *(f32x4*)(ctx + i);
    f32x4 b = *(const f32x4*)(part + i);
    *(f32x4*)(ctx + i) = a + b;
  }
}

// ================= monolithic fallback (R4) for tiny ws =================
__global__ __launch_bounds__(512, 4) void attn_mono(
    const float* __restrict__ qs, const float* __restrict__ ks,
    const float* __restrict__ vs, const int* __restrict__ vlen,
    float* __restrict__ ctx_out, float* __restrict__ attn_out)
{
  __shared__ __align__(16) unsigned short Ksm[2][KT][KROW];
  __shared__ __align__(16) unsigned short Vt [2][Dn][VROW];
  const int tid = threadIdx.x, wave = tid >> 6, lane = tid & 63;
  const int c = lane & 15, g = lane >> 4;
  const int bh = blockIdx.y, qt = blockIdx.x;
  const int b = bh >> 4, h = bh & 15;
  const int vl = vlen[b];
  const int qb = qt * QT + wave * 16;

  BF8 qf[4];
  load_q(qs + (((size_t)(b * Qn + qb + c)) * Hn + h) * Dn, qf, g);
  const int nkt_v = (vl + KT - 1) / KT;
  const float* kbase = ks + ((size_t)b * Kn * Hn + h) * Dn;
  const float* vbase = vs + ((size_t)b * Kn * Hn + h) * Dn;

  float rs = 0.f;
  stage_k(kbase, Ksm[0], tid);
  __syncthreads();
  for (int t = 0; t < nkt_v; ++t) {
    const int cur = t & 1;
    if (t + 1 < nkt_v) stage_k(kbase + (size_t)(t + 1) * KT * HD, Ksm[cur ^ 1], tid);
    #pragma unroll
    for (int nt = 0; nt < 2; ++nt) {
      f32x4 acc = {0.f, 0.f, 0.f, 0.f};
      #pragma unroll
      for (int s = 0; s < 4; ++s) {
        BF8 kf; kf.v = *(const bf16x8*)&Ksm[cur][nt * 16 + c][s * 32 + g * 8];
        acc = __builtin_amdgcn_mfma_f32_16x16x32_bf16(kf.v, qf[s].v, acc, 0, 0, 0);
      }
      const int k0 = t * KT + nt * 16 + g * 4;
      #pragma unroll
      for (int r = 0; r < 4; ++r)
        rs += (k0 + r < vl) ? __expf(acc[r] * SCALE) : 0.f;
    }
    __syncthreads();
  }
  rs += __shfl_xor(rs, 16);
  rs += __shfl_xor(rs, 32);
  const float inv = 1.0f / rs;

  f32x4 ctxa[8];
  #pragma unroll
  for (int ii = 0; ii < 8; ++ii) ctxa[ii] = (f32x4){0.f, 0.f, 0.f, 0.f};
  stage_k(kbase, Ksm[0], tid);
  stage_v(vbase, Vt[0], tid);
  __syncthreads();
  float* rowp = attn_out + ((size_t)bh * Qn + qb + c) * Kn;
  for (int t = 0; t < nkt_v; ++t) {
    const int cur = t & 1;
    if (t + 1 < nkt_v) {
      stage_k(kbase + (size_t)(t + 1) * KT * HD, Ksm[cur ^ 1], tid);
      stage_v(vbase + (size_t)(t + 1) * KT * HD, Vt[cur ^ 1], tid);
    }
    BF8 pf;
    #pragma unroll
    for (int nt = 0; nt < 2; ++nt) {
      f32x4 acc = {0.f, 0.f, 0.f, 0.f};
      #pragma unroll
      for (int s = 0; s < 4; ++s) {
        BF8 kf; kf.v = *(const bf16x8*)&Ksm[cur][nt * 16 + c][s * 32 + g * 8];
        acc = __builtin_amdgcn_mfma_f32_16x16x32_bf16(kf.v, qf[s].v, acc, 0, 0, 0);
      }
      const int k0 = t * KT + nt * 16 + g * 4;
      f32x4 p;
      #pragma unroll
      for (int r = 0; r < 4; ++r) {
        p[r] = (k0 + r < vl) ? __expf(acc[r] * SCALE) * inv : 0.f;
        pf.u[nt * 4 + r] = f2bf(p[r]);
      }
      *(f32x4*)(rowp + t * KT + nt * 16 + g * 4) = p;
    }
    #pragma unroll
    for (int n8 = 0; n8 < 8; ++n8) {
      BF8 vf; vf.v = *(const bf16x8*)&Vt[cur][n8 * 16 + c][g * 8];
      ctxa[n8] = __builtin_amdgcn_mfma_f32_16x16x32_bf16(vf.v, pf.v, ctxa[n8], 0, 0, 0);
    }
    __syncthreads();
  }
  const int col0 = nkt_v * KT;
  #pragma unroll 1
  for (int r = 0; r < 16; ++r) {
    float* zp = attn_out + ((size_t)bh * Qn + qb + r) * Kn;
    for (int c4 = col0 + lane * 4; c4 < Kn; c4 += 256)
      *(f32x4*)(zp + c4) = (f32x4){0.f, 0.f, 0.f, 0.f};
  }
  float* cp = ctx_out + (((size_t)(b * Qn + qb + c)) * Hn + h) * Dn;
  #pragma unroll
  for (int n8 = 0; n8 < 8; ++n8)
    *(f32x4*)(cp + n8 * 16 + g * 4) = ctxa[n8];
}

extern "C" void kernel_launch(void* const* d_in, const int* in_sizes, int n_in,
                              void* d_out, int out_size, void* d_ws, size_t ws_size,
                              hipStream_t stream) {
  const float* qs   = (const float*)d_in[0];
  const float* ks   = (const float*)d_in[1];
  const float* vs   = (const float*)d_in[2];
  const int*   vlen = (const int*)d_in[3];
  float* ctx  = (float*)d_out;
  float* attn = ctx + CTXN;   // outputs concatenated: ctx, attn

  const size_t needB = (size_t)(5 * NQ) * 4;        // inv + 4 rs partials (~1.25 MB)
  const size_t needA = needB + CTXN * 4;            // + ctx partial (~34.8 MB)

  if (ws_size < needB) {   // deterministic fallback: monolithic two-pass
    attn_mono<<<dim3(Qn / QT, B_ * Hn), 512, 0, stream>>>(qs, ks, vs, vlen, ctx, attn);
    return;
  }
  float* inv_ws   = (float*)d_ws;
  float* rs_ws    = inv_ws + NQ;
  float* ctx_part = rs_ws + 4 * NQ;
  const int kc2 = (ws_size >= needA) ? 2 : 1;

  sum_k<<<dim3(2048), 512, 0, stream>>>(qs, ks, vlen, rs_ws);
  inv_k<<<dim3(NQ / 256), 256, 0, stream>>>(rs_ws, inv_ws);
  attn_pv<<<dim3(kc2, Qn / QT, B_ * Hn), 512, 0, stream>>>(
      qs, ks, vs, vlen, inv_ws, ctx, (kc2 == 2) ? ctx_part : ctx, attn, Kn / kc2);
  if (kc2 == 2) fold_k<<<dim3(2048), 256, 0, stream>>>(ctx, ctx_part);
}

// Round 8
// 217.329 us; speedup vs baseline: 2.7790x; 1.2775x over previous
//
#include <hip/hip_runtime.h>
#include <hip/hip_bf16.h>
#include <stdint.h>

#define B_ 2
#define Qn 2048
#define Kn 2048
#define Hn 16
#define Dn 128
#define QT 128     // q rows per block (8 waves x 16)
#define KT 64      // keys per tile, pass 2
#define KT1 128    // keys per tile, pass 1
#define HD (Hn*Dn)
#define KROW 132   // K row stride in shorts (264 B)
#define VROW 72    // Vt row stride in shorts (144 B)

typedef __bf16 bf16x8 __attribute__((ext_vector_type(8)));
typedef __bf16 bf16x4 __attribute__((ext_vector_type(4)));
typedef float f32x4 __attribute__((ext_vector_type(4)));

union BF8 { __bf16 e[8]; bf16x8 v; };

#define SCALE 0.088388347648318447f  // 1/sqrt(128)

struct SMp2 { unsigned short K[2][KT][KROW]; unsigned short V[2][Dn][VROW]; };
union SMu { SMp2 p2; unsigned short K1[2][KT1][KROW]; };

// lgkm-only barrier: orders LDS ops across the block WITHOUT draining vmcnt
// (attn stores & prefetch loads stay in flight). Safe for the dbuf scheme:
// each wave's own ds_writes/ds_reads are complete before s_barrier.
__device__ __forceinline__ void bar_lgkm() {
  asm volatile("s_waitcnt lgkmcnt(0)" ::: "memory");
  __builtin_amdgcn_s_barrier();
  __builtin_amdgcn_sched_barrier(0);
}

__device__ __forceinline__ bf16x4 cvt4(f32x4 a) {
  bf16x4 r;
  r[0] = (__bf16)a[0]; r[1] = (__bf16)a[1];
  r[2] = (__bf16)a[2]; r[3] = (__bf16)a[3];
  return r;
}

__device__ __forceinline__ void stage_k64(const float* kb, unsigned short (*dst)[KROW], int tid) {
  #pragma unroll
  for (int ii = 0; ii < 4; ++ii) {
    int chunk = ii * 512 + tid;           // 64 rows x 32 chunks
    int row = chunk >> 5, cv = chunk & 31;
    f32x4 a = *(const f32x4*)(kb + (size_t)row * HD + cv * 4);
    *(bf16x4*)&dst[row][cv * 4] = cvt4(a);
  }
}

__device__ __forceinline__ void stage_k128(const float* kb, unsigned short (*dst)[KROW], int tid) {
  #pragma unroll
  for (int ii = 0; ii < 8; ++ii) {
    int chunk = ii * 512 + tid;           // 128 rows x 32 chunks
    int row = chunk >> 5, cv = chunk & 31;
    f32x4 a = *(const f32x4*)(kb + (size_t)row * HD + cv * 4);
    *(bf16x4*)&dst[row][cv * 4] = cvt4(a);
  }
}

// V^T: chunk (kk,gg) of row d holds keys kk*32 + {4gg..4gg+3, 16+4gg..16+4gg+3}
__device__ __forceinline__ void stage_v64(const float* vb, unsigned short (*dst)[VROW], int tid) {
  int d = tid & 127, t0 = tid >> 7;       // t0 in [0,4)
  const float* colp = vb + d;
  #pragma unroll
  for (int rr = 0; rr < 2; ++rr) {
    int idx = rr * 4 + t0;                // [0,8)
    int kk = idx >> 2, gg = idx & 3;
    int kb0 = kk * 32 + gg * 4;
    BF8 t;
    #pragma unroll
    for (int j = 0; j < 4; ++j) {
      t.e[j]     = (__bf16)colp[(size_t)(kb0 + j) * HD];
      t.e[4 + j] = (__bf16)colp[(size_t)(kb0 + 16 + j) * HD];
    }
    *(bf16x8*)&dst[d][kk * 32 + gg * 8] = t.v;
  }
}

__device__ __forceinline__ void load_q(const float* qrow, BF8* qf, int g) {
  #pragma unroll
  for (int s = 0; s < 4; ++s) {
    f32x4 a0 = *(const f32x4*)(qrow + s * 32 + g * 8);
    f32x4 a1 = *(const f32x4*)(qrow + s * 32 + g * 8 + 4);
    #pragma unroll
    for (int j = 0; j < 4; ++j) { qf[s].e[j] = (__bf16)a0[j]; qf[s].e[4 + j] = (__bf16)a1[j]; }
  }
}

__global__ __launch_bounds__(512, 4) void attn_fwd(
    const float* __restrict__ qs, const float* __restrict__ ks,
    const float* __restrict__ vs, const int* __restrict__ vlen,
    float* __restrict__ ctx_out, float* __restrict__ attn_out)
{
  __shared__ __align__(16) SMu sm;

  const int tid = threadIdx.x, wave = tid >> 6, lane = tid & 63;
  const int c = lane & 15, g = lane >> 4;

  // XCD-aware decode: xcd = L&7 pins a bh-group to one XCD
  const int L   = blockIdx.x;
  const int xcd = L & 7;
  const int i5  = L >> 3;                 // 0..63
  const int bh  = ((i5 & 3) << 3) + xcd;
  const int qt  = i5 >> 2;                // 0..15
  const int b   = bh >> 4, h = bh & 15;
  const int vl  = vlen[b];
  const int qb  = qt * QT + wave * 16;

  BF8 qf[4];
  load_q(qs + (((size_t)(b * Qn + qb + c)) * Hn + h) * Dn, qf, g);
  const float* kbase = ks + ((size_t)b * Kn * Hn + h) * Dn;
  const float* vbase = vs + ((size_t)b * Kn * Hn + h) * Dn;

  // ---------------- pass 1: row sums of exp (KT1=128 tiles) ----------------
  float rs = 0.f;
  {
    const int nkt = (vl + KT1 - 1) / KT1;
    stage_k128(kbase, sm.K1[0], tid);
    bar_lgkm();
    for (int t = 0; t < nkt; ++t) {
      const int cur = t & 1;
      if (t + 1 < nkt) stage_k128(kbase + (size_t)(t + 1) * KT1 * HD, sm.K1[cur ^ 1], tid);
      #pragma unroll
      for (int nt = 0; nt < 8; ++nt) {
        f32x4 acc = {0.f, 0.f, 0.f, 0.f};
        #pragma unroll
        for (int s = 0; s < 4; ++s) {
          BF8 kf; kf.v = *(const bf16x8*)&sm.K1[cur][nt * 16 + c][s * 32 + g * 8];
          acc = __builtin_amdgcn_mfma_f32_16x16x32_bf16(kf.v, qf[s].v, acc, 0, 0, 0);
        }
        const int k0 = t * KT1 + nt * 16 + g * 4;
        #pragma unroll
        for (int r = 0; r < 4; ++r)
          rs += (k0 + r < vl) ? __expf(acc[r] * SCALE) : 0.f;
      }
      bar_lgkm();
    }
  }
  rs += __shfl_xor(rs, 16);
  rs += __shfl_xor(rs, 32);
  const float inv = 1.0f / rs;   // row sum for q-row (qb + c)

  // ---------------- pass 2: attn writes + PV (KT=64 tiles) ----------------
  f32x4 ctxa[8];
  #pragma unroll
  for (int ii = 0; ii < 8; ++ii) ctxa[ii] = (f32x4){0.f, 0.f, 0.f, 0.f};

  const int nkt = (vl + KT - 1) / KT;
  stage_k64(kbase, sm.p2.K[0], tid);
  stage_v64(vbase, sm.p2.V[0], tid);
  bar_lgkm();
  float* rowp = attn_out + ((size_t)bh * Qn + qb + c) * Kn;
  for (int t = 0; t < nkt; ++t) {
    const int cur = t & 1;
    if (t + 1 < nkt) {
      stage_k64(kbase + (size_t)(t + 1) * KT * HD, sm.p2.K[cur ^ 1], tid);
      stage_v64(vbase + (size_t)(t + 1) * KT * HD, sm.p2.V[cur ^ 1], tid);
    }
    // S^T tile: lane (c,g) holds S[q=c][k = t*64 + nt*16 + g*4 + r]
    BF8 pf[2];
    #pragma unroll
    for (int nt = 0; nt < 4; ++nt) {
      f32x4 acc = {0.f, 0.f, 0.f, 0.f};
      #pragma unroll
      for (int s = 0; s < 4; ++s) {
        BF8 kf; kf.v = *(const bf16x8*)&sm.p2.K[cur][nt * 16 + c][s * 32 + g * 8];
        acc = __builtin_amdgcn_mfma_f32_16x16x32_bf16(kf.v, qf[s].v, acc, 0, 0, 0);
      }
      const int k0 = t * KT + nt * 16 + g * 4;
      f32x4 p;
      #pragma unroll
      for (int r = 0; r < 4; ++r) {
        p[r] = (k0 + r < vl) ? __expf(acc[r] * SCALE) * inv : 0.f;
        pf[nt >> 1].e[(nt & 1) * 4 + r] = (__bf16)p[r];
      }
      *(f32x4*)(rowp + t * KT + nt * 16 + g * 4) = p;   // 16B vector attn store
    }
    // PV (swapped): ctx^T = V^T * P^T, shared per-32-key permutation {4g+j, 16+4g+j}
    #pragma unroll
    for (int kk = 0; kk < 2; ++kk)
      #pragma unroll
      for (int n8 = 0; n8 < 8; ++n8) {
        BF8 vf; vf.v = *(const bf16x8*)&sm.p2.V[cur][n8 * 16 + c][kk * 32 + g * 8];
        ctxa[n8] = __builtin_amdgcn_mfma_f32_16x16x32_bf16(vf.v, pf[kk].v, ctxa[n8], 0, 0, 0);
      }
    bar_lgkm();
  }

  // ---------------- vectorized zero-fill of fully-masked attn columns ----------------
  const int col0 = nkt * KT;   // cols >= col0 are exactly 0
  #pragma unroll 1
  for (int r = 0; r < 16; ++r) {
    float* zp = attn_out + ((size_t)bh * Qn + qb + r) * Kn;   // wave's own 16 rows
    for (int c4 = col0 + lane * 4; c4 < Kn; c4 += 256)
      *(f32x4*)(zp + c4) = (f32x4){0.f, 0.f, 0.f, 0.f};
  }

  // ---------------- epilogue: ctx[q=c][d = n8*16 + g*4 + r] ----------------
  float* cp = ctx_out + (((size_t)(b * Qn + qb + c)) * Hn + h) * Dn;
  #pragma unroll
  for (int n8 = 0; n8 < 8; ++n8)
    *(f32x4*)(cp + n8 * 16 + g * 4) = ctxa[n8];
}

extern "C" void kernel_launch(void* const* d_in, const int* in_sizes, int n_in,
                              void* d_out, int out_size, void* d_ws, size_t ws_size,
                              hipStream_t stream) {
  const float* qs   = (const float*)d_in[0];
  const float* ks   = (const float*)d_in[1];
  const float* vs   = (const float*)d_in[2];
  const int*   vlen = (const int*)d_in[3];
  float* ctx  = (float*)d_out;
  float* attn = ctx + (size_t)B_ * Qn * Hn * Dn;   // outputs concatenated: ctx, attn
  attn_fwd<<<dim3((Qn / QT) * B_ * Hn), 512, 0, stream>>>(qs, ks, vs, vlen, ctx, attn);
}

// Round 9
// 215.581 us; speedup vs baseline: 2.8016x; 1.0081x over previous
//
#include <hip/hip_runtime.h>
#include <hip/hip_bf16.h>
#include <stdint.h>

#define B_ 2
#define Qn 2048
#define Kn 2048
#define Hn 16
#define Dn 128
#define QT 256     // q rows per block (8 waves x 32)
#define KT 128     // keys per tile (both passes)
#define HD (Hn*Dn)
#define KROW 132   // K row stride in shorts (264 B)
#define VROW 136   // Vt row stride in shorts (272 B)

typedef __bf16 bf16x8 __attribute__((ext_vector_type(8)));
typedef __bf16 bf16x4 __attribute__((ext_vector_type(4)));
typedef float f32x4 __attribute__((ext_vector_type(4)));
typedef float f32x16 __attribute__((ext_vector_type(16)));

union BF8 { __bf16 e[8]; bf16x8 v; };

#define SCALE 0.088388347648318447f  // 1/sqrt(128)

struct SMs {
  unsigned short K[2][KT][KROW];   // row-major K (bf16)
  unsigned short V[2][Dn][VROW];   // V^T, 8-key chunks in C-layout key order
};

// lgkm-only barrier: orders LDS ops across the block WITHOUT draining vmcnt
__device__ __forceinline__ void bar_lgkm() {
  asm volatile("s_waitcnt lgkmcnt(0)" ::: "memory");
  __builtin_amdgcn_s_barrier();
  __builtin_amdgcn_sched_barrier(0);
}

__device__ __forceinline__ bf16x4 cvt4(f32x4 a) {
  bf16x4 r;
  r[0] = (__bf16)a[0]; r[1] = (__bf16)a[1];
  r[2] = (__bf16)a[2]; r[3] = (__bf16)a[3];
  return r;
}

// K tile: 128 rows x 32 f32x4-chunks = 4096 chunks, 512 threads -> 8 each
__device__ __forceinline__ void stage_k(const float* kb, unsigned short (*dst)[KROW], int tid) {
  #pragma unroll
  for (int ii = 0; ii < 8; ++ii) {
    int chunk = ii * 512 + tid;
    int row = chunk >> 5, cv = chunk & 31;
    f32x4 a = *(const f32x4*)(kb + (size_t)row * HD + cv * 4);
    *(bf16x4*)&dst[row][cv * 4] = cvt4(a);
  }
}

// V^T: chunk idx (m=idx>>2, s2=(idx>>1)&1, hi=idx&1) of row d holds keys
// m*32 + s2*16 + 4*hi + {0..3, 8..11}  (mirrors the 32x32 C/D key layout)
__device__ __forceinline__ void stage_v(const float* vb, unsigned short (*dst)[VROW], int tid) {
  int d = tid & 127, c0 = tid >> 7;   // c0 in [0,4)
  const float* colp = vb + d;
  #pragma unroll
  for (int rr = 0; rr < 4; ++rr) {
    int idx = rr * 4 + c0;            // [0,16)
    int base = (idx >> 2) * 32 + ((idx >> 1) & 1) * 16 + (idx & 1) * 4;
    BF8 t;
    #pragma unroll
    for (int j = 0; j < 4; ++j) {
      t.e[j]     = (__bf16)colp[(size_t)(base + j) * HD];
      t.e[4 + j] = (__bf16)colp[(size_t)(base + 8 + j) * HD];
    }
    *(bf16x8*)&dst[d][idx * 8] = t.v;
  }
}

__global__ __launch_bounds__(512, 2) void attn_fwd(
    const float* __restrict__ qs, const float* __restrict__ ks,
    const float* __restrict__ vs, const int* __restrict__ vlen,
    float* __restrict__ ctx_out, float* __restrict__ attn_out)
{
  __shared__ __align__(16) SMs sm;

  const int tid = threadIdx.x, wave = tid >> 6, lane = tid & 63;
  const int l31 = lane & 31, hi = lane >> 5;

  // XCD-aware decode (256 blocks, all co-resident: 1 block/CU)
  const int L   = blockIdx.x;
  const int xcd = L & 7;
  const int i5  = L >> 3;                 // 0..31
  const int bh  = ((i5 & 3) << 3) + xcd;
  const int qt  = i5 >> 2;                // 0..7
  const int b   = bh >> 4, h = bh & 15;
  const int vl  = vlen[b];
  const int qbw = qt * QT + wave * 32;    // wave's q base (32 rows)

  // ---- Q fragments: step s covers d in [s*16, s*16+16); lane elems d = s*16 + hi*8 + j ----
  BF8 qf[8];
  {
    const float* qrow = qs + (((size_t)(b * Qn + qbw + l31)) * Hn + h) * Dn;
    #pragma unroll
    for (int s = 0; s < 8; ++s) {
      int d0 = s * 16 + hi * 8;
      f32x4 a0 = *(const f32x4*)(qrow + d0);
      f32x4 a1 = *(const f32x4*)(qrow + d0 + 4);
      #pragma unroll
      for (int j = 0; j < 4; ++j) { qf[s].e[j] = (__bf16)a0[j]; qf[s].e[4 + j] = (__bf16)a1[j]; }
    }
  }

  const float* kbase = ks + ((size_t)b * Kn * Hn + h) * Dn;
  const float* vbase = vs + ((size_t)b * Kn * Hn + h) * Dn;
  const int nkt = (vl + KT - 1) / KT;

  // ---------------- pass 1: row sums of exp (S^T = K * Q^T, 32x32 tiles) ----------------
  float rs = 0.f;
  stage_k(kbase, sm.K[0], tid);
  bar_lgkm();
  for (int t = 0; t < nkt; ++t) {
    const int cur = t & 1;
    if (t + 1 < nkt) stage_k(kbase + (size_t)(t + 1) * KT * HD, sm.K[cur ^ 1], tid);
    #pragma unroll
    for (int m = 0; m < 4; ++m) {
      f32x16 acc;
      #pragma unroll
      for (int i = 0; i < 16; ++i) acc[i] = 0.f;
      #pragma unroll
      for (int s = 0; s < 8; ++s) {
        BF8 kf; kf.v = *(const bf16x8*)&sm.K[cur][m * 32 + l31][s * 16 + hi * 8];
        acc = __builtin_amdgcn_mfma_f32_32x32x16_bf16(kf.v, qf[s].v, acc, 0, 0, 0);
      }
      const int kb0 = t * KT + m * 32 + hi * 4;
      #pragma unroll
      for (int reg = 0; reg < 16; ++reg) {
        int key = kb0 + (reg & 3) + 8 * (reg >> 2);
        rs += (key < vl) ? __expf(acc[reg] * SCALE) : 0.f;
      }
    }
    bar_lgkm();
  }
  rs += __shfl_xor(rs, 32);       // combine hi halves (q = l31 for both)
  const float inv = 1.0f / rs;    // row sum for q-row (qbw + l31)

  // ---------------- pass 2: attn writes + PV ----------------
  f32x16 ctxa[4];
  #pragma unroll
  for (int ch = 0; ch < 4; ++ch)
    #pragma unroll
    for (int i = 0; i < 16; ++i) ctxa[ch][i] = 0.f;

  stage_k(kbase, sm.K[0], tid);
  stage_v(vbase, sm.V[0], tid);
  bar_lgkm();
  float* rowp = attn_out + ((size_t)bh * Qn + qbw + l31) * Kn;
  for (int t = 0; t < nkt; ++t) {
    const int cur = t & 1;
    if (t + 1 < nkt) {
      stage_k(kbase + (size_t)(t + 1) * KT * HD, sm.K[cur ^ 1], tid);
      stage_v(vbase + (size_t)(t + 1) * KT * HD, sm.V[cur ^ 1], tid);
    }
    #pragma unroll
    for (int m = 0; m < 4; ++m) {
      f32x16 acc;
      #pragma unroll
      for (int i = 0; i < 16; ++i) acc[i] = 0.f;
      #pragma unroll
      for (int s = 0; s < 8; ++s) {
        BF8 kf; kf.v = *(const bf16x8*)&sm.K[cur][m * 32 + l31][s * 16 + hi * 8];
        acc = __builtin_amdgcn_mfma_f32_32x32x16_bf16(kf.v, qf[s].v, acc, 0, 0, 0);
      }
      const int kb0 = t * KT + m * 32;
      BF8 pf0, pf1;
      #pragma unroll
      for (int r4 = 0; r4 < 4; ++r4) {
        f32x4 p;
        #pragma unroll
        for (int rr = 0; rr < 4; ++rr) {
          int key = kb0 + r4 * 8 + hi * 4 + rr;
          float v = (key < vl) ? __expf(acc[r4 * 4 + rr] * SCALE) * inv : 0.f;
          p[rr] = v;
          if (r4 < 2) pf0.e[r4 * 4 + rr] = (__bf16)v;
          else        pf1.e[(r4 - 2) * 4 + rr] = (__bf16)v;
        }
        *(f32x4*)(rowp + kb0 + r4 * 8 + hi * 4) = p;   // 16B vector attn store
      }
      // PV (swapped): ctx^T chunk = V^T * P^T; A/B share the C-derived key order
      #pragma unroll
      for (int ch = 0; ch < 4; ++ch) {
        BF8 v0; v0.v = *(const bf16x8*)&sm.V[cur][ch * 32 + l31][(m * 4 + hi) * 8];
        ctxa[ch] = __builtin_amdgcn_mfma_f32_32x32x16_bf16(v0.v, pf0.v, ctxa[ch], 0, 0, 0);
        BF8 v1; v1.v = *(const bf16x8*)&sm.V[cur][ch * 32 + l31][(m * 4 + 2 + hi) * 8];
        ctxa[ch] = __builtin_amdgcn_mfma_f32_32x32x16_bf16(v1.v, pf1.v, ctxa[ch], 0, 0, 0);
      }
    }
    bar_lgkm();
  }

  // ---------------- vectorized zero-fill of fully-masked attn columns ----------------
  const int col0 = nkt * KT;
  #pragma unroll 1
  for (int r = 0; r < 32; ++r) {
    float* zp = attn_out + ((size_t)bh * Qn + qbw + r) * Kn;
    for (int c4 = col0 + lane * 4; c4 < Kn; c4 += 256)
      *(f32x4*)(zp + c4) = (f32x4){0.f, 0.f, 0.f, 0.f};
  }

  // ---------------- epilogue: ctx[q=l31][d = ch*32 + r4*8 + hi*4 + rr] ----------------
  float* cp = ctx_out + (((size_t)(b * Qn + qbw + l31)) * Hn + h) * Dn;
  #pragma unroll
  for (int ch = 0; ch < 4; ++ch)
    #pragma unroll
    for (int r4 = 0; r4 < 4; ++r4) {
      f32x4 o;
      #pragma unroll
      for (int rr = 0; rr < 4; ++rr) o[rr] = ctxa[ch][r4 * 4 + rr];
      *(f32x4*)(cp + ch * 32 + r4 * 8 + hi * 4) = o;
    }
}

extern "C" void kernel_launch(void* const* d_in, const int* in_sizes, int n_in,
                              void* d_out, int out_size, void* d_ws, size_t ws_size,
                              hipStream_t stream) {
  const float* qs   = (const float*)d_in[0];
  const float* ks   = (const float*)d_in[1];
  const float* vs   = (const float*)d_in[2];
  const int*   vlen = (const int*)d_in[3];
  float* ctx  = (float*)d_out;
  float* attn = ctx + (size_t)B_ * Qn * Hn * Dn;   // outputs concatenated: ctx, attn
  attn_fwd<<<dim3((Qn / QT) * B_ * Hn), 512, 0, stream>>>(qs, ks, vs, vlen, ctx, attn);
}